// Round 4
// baseline (1016.326 us; speedup 1.0000x reference)
//
#include <hip/hip_runtime.h>

// Problem constants (match reference)
#define N_EMBD 1024
#define N_HEAD 16
#define HD 64            // head dim
#define BSZ 4
#define TSEQ 2048
#define MROWS (BSZ * TSEQ)   // 8192

using bf16x8 = __attribute__((ext_vector_type(8))) short;
using f32x4  = __attribute__((ext_vector_type(4))) float;

// Raw-bit bf16 helpers (RN-even).
__device__ __forceinline__ ushort f2bf(float f) {
    uint u = __float_as_uint(f);
    u += 0x7FFFu + ((u >> 16) & 1u);
    return (ushort)(u >> 16);
}
__device__ __forceinline__ float bf2f(ushort h) {
    return __uint_as_float(((uint)h) << 16);
}

// ---------------------------------------------------------------------------
// split_bf16: A (f32) -> H = bf16(A), L = bf16(A - H).  4 elems/thread.
// ---------------------------------------------------------------------------
__global__ __launch_bounds__(256) void split_bf16(const float* __restrict__ A,
                                                  ushort* __restrict__ H,
                                                  ushort* __restrict__ L)
{
    const size_t i = ((size_t)blockIdx.x * 256 + threadIdx.x) * 4;
    const float4 v = *(const float4*)&A[i];
    ushort4 h, l;
    h.x = f2bf(v.x); l.x = f2bf(v.x - bf2f(h.x));
    h.y = f2bf(v.y); l.y = f2bf(v.y - bf2f(h.y));
    h.z = f2bf(v.z); l.z = f2bf(v.z - bf2f(h.z));
    h.w = f2bf(v.w); l.w = f2bf(v.w - bf2f(h.w));
    *(ushort4*)&H[i] = h;
    *(ushort4*)&L[i] = l;
}

// ---------------------------------------------------------------------------
// transpose_split: W [K,N] f32 -> Th, Tl [N,K] bf16 (hi/lo split).
// ---------------------------------------------------------------------------
__global__ __launch_bounds__(256) void transpose_split(
    const float* __restrict__ W, ushort* __restrict__ Th, ushort* __restrict__ Tl,
    int K, int N)
{
    __shared__ float t[32][33];
    const int k0 = blockIdx.y * 32;
    const int n0 = blockIdx.x * 32;
    const int c = threadIdx.x & 31;
    const int r = threadIdx.x >> 5;   // 0..7
    #pragma unroll
    for (int i = 0; i < 4; ++i)
        t[r + i * 8][c] = W[(size_t)(k0 + r + i * 8) * N + n0 + c];
    __syncthreads();
    #pragma unroll
    for (int i = 0; i < 4; ++i) {
        const float v = t[c][r + i * 8];           // = W[k0+c][n0+r+i*8]
        const ushort hb = f2bf(v);
        const ushort lb = f2bf(v - bf2f(hb));
        const size_t o = (size_t)(n0 + r + i * 8) * K + k0 + c;
        Th[o] = hb;
        Tl[o] = lb;
    }
}

// ---------------------------------------------------------------------------
// transpose_v: qkvh v-part -> vth [b,h,d,t] bf16.  64x64 tiles via LDS.
// Row pitch 72 shorts (144 B) keeps float4 LDS ops unsplit.
// ---------------------------------------------------------------------------
__global__ __launch_bounds__(256) void transpose_v(
    const ushort* __restrict__ qkvh, ushort* __restrict__ vth)
{
    __shared__ __align__(16) ushort tr[64][72];
    const int t0 = blockIdx.x * 64;
    const int h  = blockIdx.y;
    const int b  = blockIdx.z;
    const int r  = threadIdx.x >> 2;         // 0..63
    const int c4 = (threadIdx.x & 3) * 16;   // 0,16,32,48

    const size_t inb = ((size_t)(b * TSEQ + t0 + r)) * (3 * N_EMBD) + 2 * N_EMBD + h * HD + c4;
    *(float4*)&tr[r][c4]     = *(const float4*)&qkvh[inb];
    *(float4*)&tr[r][c4 + 8] = *(const float4*)&qkvh[inb + 8];
    __syncthreads();

    ushort v[16] __attribute__((aligned(16)));
    #pragma unroll
    for (int u = 0; u < 16; ++u) v[u] = tr[c4 + u][r];   // = V[t0+c4+u][d=r]
    const size_t ob = (((size_t)(b * N_HEAD + h)) * HD + r) * TSEQ + t0 + c4;
    *(float4*)&vth[ob]     = ((const float4*)v)[0];
    *(float4*)&vth[ob + 8] = ((const float4*)v)[1];
}

// ---------------------------------------------------------------------------
// Split-bf16 MFMA GEMM.  C[M,N] = A[M,K] @ B^T[N,K] + bias.
// ASPLIT: 3-term (AhBh+AlBh+AhBl); else 2-term (AhBh+AhBl).
// OUTBF16: hi/lo bf16 planes; else f32.
// 128x128 tile, BK=32, 4 waves, 64x64/wave, 4x4 16x16x32 frags.
// LDS pitch 40 shorts = 80 B (16B-mult -> single ds_*_b128; 2-way banks).
// Epilogue stages through LDS and writes 16 B/lane coalesced rows.
// ---------------------------------------------------------------------------
#define LDP 40

template<bool ASPLIT, bool OUTBF16>
__global__ __launch_bounds__(256) void gemm_mfma(
    const ushort* __restrict__ Ah, const ushort* __restrict__ Al,
    const ushort* __restrict__ Bh, const ushort* __restrict__ Bl,
    const float* __restrict__ bias,
    float* __restrict__ Cf, ushort* __restrict__ Ch, ushort* __restrict__ Cl,
    int M, int N, int K)
{
    // K-loop: 4 planes x 128 rows x LDP(40) = 20480 shorts (40960 B)
    // epilogue bf16: 4 waves x 64 x 72   = 18432 shorts
    // epilogue f32 : 4 waves x 32 x 68 f32 = 34816 B
    __shared__ __align__(16) short lds_raw[20480];
    #define PL(p, r) (lds_raw + ((p) * 128 + (r)) * LDP)

    const int tid  = threadIdx.x;
    const int wave = tid >> 6;
    const int lane = tid & 63;
    const int wr   = wave >> 1;
    const int wc   = wave & 1;
    const int row0 = blockIdx.y * 128;
    const int col0 = blockIdx.x * 128;

    const int srow = tid >> 2;           // 0..63
    const int soff = (tid & 3) * 8;      // 0,8,16,24

    const int fr = lane & 15;
    const int fq = lane >> 4;
    const int ko = fq * 8;

    f32x4 acc[4][4] = {};

    for (int k0 = 0; k0 < K; k0 += 32) {
        float4 pa[2][2], pb[2][2];
        #pragma unroll
        for (int it = 0; it < 2; ++it) {
            const int r = srow + it * 64;
            const size_t ga = (size_t)(row0 + r) * K + k0 + soff;
            const size_t gb = (size_t)(col0 + r) * K + k0 + soff;
            pa[it][0] = *(const float4*)&Ah[ga];
            if (ASPLIT) pa[it][1] = *(const float4*)&Al[ga];
            pb[it][0] = *(const float4*)&Bh[gb];
            pb[it][1] = *(const float4*)&Bl[gb];
        }
        __syncthreads();
        #pragma unroll
        for (int it = 0; it < 2; ++it) {
            const int r = srow + it * 64;
            *(float4*)(PL(0, r) + soff) = pa[it][0];
            if (ASPLIT) *(float4*)(PL(1, r) + soff) = pa[it][1];
            *(float4*)(PL(2, r) + soff) = pb[it][0];
            *(float4*)(PL(3, r) + soff) = pb[it][1];
        }
        __syncthreads();

        bf16x8 a_h[4], a_l[4], b_h[4], b_l[4];
        #pragma unroll
        for (int m = 0; m < 4; ++m) {
            a_h[m] = *(const bf16x8*)(PL(0, wr * 64 + m * 16 + fr) + ko);
            if (ASPLIT) a_l[m] = *(const bf16x8*)(PL(1, wr * 64 + m * 16 + fr) + ko);
        }
        #pragma unroll
        for (int n = 0; n < 4; ++n) {
            b_h[n] = *(const bf16x8*)(PL(2, wc * 64 + n * 16 + fr) + ko);
            b_l[n] = *(const bf16x8*)(PL(3, wc * 64 + n * 16 + fr) + ko);
        }

        #pragma unroll
        for (int m = 0; m < 4; ++m)
            #pragma unroll
            for (int n = 0; n < 4; ++n) {
                acc[m][n] = __builtin_amdgcn_mfma_f32_16x16x32_bf16(a_h[m], b_h[n], acc[m][n], 0, 0, 0);
                if (ASPLIT)
                    acc[m][n] = __builtin_amdgcn_mfma_f32_16x16x32_bf16(a_l[m], b_h[n], acc[m][n], 0, 0, 0);
                acc[m][n] = __builtin_amdgcn_mfma_f32_16x16x32_bf16(a_h[m], b_l[n], acc[m][n], 0, 0, 0);
            }
    }

    // ---- epilogue: D col = lane&15, row = (lane>>4)*4 + j  [HW-verified] ----
    // bias per lane (4 cols this lane ever touches)
    float bv[4];
    #pragma unroll
    for (int n = 0; n < 4; ++n) bv[n] = bias[col0 + wc * 64 + n * 16 + fr];

    if (OUTBF16) {
        short* wbuf = lds_raw + wave * (64 * 72);   // 64 rows x 72 shorts (144 B)
        #pragma unroll
        for (int t = 0; t < 2; ++t) {
            __syncthreads();   // t=0: also protects K-loop planes from overwrite
            #pragma unroll
            for (int m = 0; m < 4; ++m)
                #pragma unroll
                for (int j = 0; j < 4; ++j)
                    #pragma unroll
                    for (int n = 0; n < 4; ++n) {
                        const float o = acc[m][n][j] + bv[n];
                        const ushort hb = f2bf(o);
                        wbuf[(m * 16 + fq * 4 + j) * 72 + n * 16 + fr] =
                            (short)(t == 0 ? hb : f2bf(o - bf2f(hb)));
                    }
            __syncthreads();
            ushort* dst = (t == 0) ? Ch : Cl;
            #pragma unroll
            for (int i = 0; i < 8; ++i) {
                const int r = i * 8 + (lane >> 3);
                const bf16x8 v = *(const bf16x8*)&wbuf[r * 72 + (lane & 7) * 8];
                *(bf16x8*)&dst[(size_t)(row0 + wr * 64 + r) * N
                               + col0 + wc * 64 + (lane & 7) * 8] = v;
            }
        }
    } else {
        float* fbuf = (float*)lds_raw + wave * (32 * 68);  // 32 rows x 68 f32 (272 B)
        #pragma unroll
        for (int half = 0; half < 2; ++half) {
            __syncthreads();
            #pragma unroll
            for (int m2 = 0; m2 < 2; ++m2) {
                const int m = half * 2 + m2;
                #pragma unroll
                for (int j = 0; j < 4; ++j)
                    #pragma unroll
                    for (int n = 0; n < 4; ++n)
                        fbuf[(m2 * 16 + fq * 4 + j) * 68 + n * 16 + fr] = acc[m][n][j] + bv[n];
            }
            __syncthreads();
            #pragma unroll
            for (int i = 0; i < 8; ++i) {
                const int r = i * 4 + (lane >> 4);
                const float4 v = *(const float4*)&fbuf[r * 68 + (lane & 15) * 4];
                *(float4*)&Cf[(size_t)(row0 + wr * 64 + half * 32 + r) * N
                              + col0 + wc * 64 + (lane & 15) * 4] = v;
            }
        }
    }
    #undef PL
}

// ---------------------------------------------------------------------------
// MFMA flash attention (causal).  8 waves x 16 q-rows; KBLK 64.
// S^T = mfma(K, Q); P via wave-private LDS; O^T = mfma(V^T, P).
// All LDS rows padded to 72 shorts (144 B) -> single ds_*_b128.
// ---------------------------------------------------------------------------
__global__ __launch_bounds__(512, 4) void flash_attn_mfma(
    const ushort* __restrict__ qkvh, const ushort* __restrict__ qkvl,
    const ushort* __restrict__ vth, ushort* __restrict__ ath)
{
    __shared__ __align__(16) short Kh[64][72];          //  9216 B
    __shared__ __align__(16) short Kl[64][72];          //  9216 B
    __shared__ __align__(16) short Vs[64][72];          //  9216 B  [d][k_local]
    __shared__ __align__(16) short Pw[8][2][16][72];    // 36864 B [wave][hi/lo][q][k]

    const int tid  = threadIdx.x;
    const int wave = tid >> 6;
    const int lane = tid & 63;
    const int fr = lane & 15;
    const int g  = lane >> 4;
    const int q0 = blockIdx.x * 128;
    const int h  = blockIdx.y;
    const int b  = blockIdx.z;
    const int qw = q0 + wave * 16;       // wave's first q row
    const int qg = qw + fr;              // this lane's q (B-col)

    const size_t qrow = ((size_t)(b * TSEQ + qg)) * (3 * N_EMBD) + h * HD + 8 * g;
    const bf16x8 qh0 = *(const bf16x8*)&qkvh[qrow];
    const bf16x8 qh1 = *(const bf16x8*)&qkvh[qrow + 32];
    const bf16x8 ql0 = *(const bf16x8*)&qkvl[qrow];
    const bf16x8 ql1 = *(const bf16x8*)&qkvl[qrow + 32];

    f32x4 O[4] = {};
    float mrun = -1e30f, lrun = 0.f;

    const int sr = tid >> 3;             // 0..63
    const int sc = (tid & 7) * 8;        // 0..56
    const ushort* kgh = qkvh + ((size_t)(b * TSEQ + sr)) * (3 * N_EMBD) + N_EMBD + h * HD + sc;
    const ushort* kgl = qkvl + ((size_t)(b * TSEQ + sr)) * (3 * N_EMBD) + N_EMBD + h * HD + sc;
    const ushort* vg  = vth + (((size_t)(b * N_HEAD + h)) * HD + sr) * TSEQ + sc;

    const int nt = q0 / 64 + 2;
    for (int kt = 0; kt < nt; ++kt) {
        const float4 rkh = *(const float4*)(kgh + (size_t)kt * 64 * 3 * N_EMBD);
        const float4 rkl = *(const float4*)(kgl + (size_t)kt * 64 * 3 * N_EMBD);
        const float4 rv  = *(const float4*)(vg + kt * 64);
        __syncthreads();                 // prior tile reads done
        *(float4*)&Kh[sr][sc] = rkh;
        *(float4*)&Kl[sr][sc] = rkl;
        *(float4*)&Vs[sr][sc] = rv;
        __syncthreads();

        if (kt * 64 > qw + 15) continue;     // fully masked for this wave

        // ---- QK^T: S^T[k][q], frag kf covers k_local = kf*16 + 4g + j ----
        f32x4 s[4] = {};
        #pragma unroll
        for (int kf = 0; kf < 4; ++kf) {
            const bf16x8 kh0 = *(const bf16x8*)&Kh[kf * 16 + fr][8 * g];
            const bf16x8 kl0 = *(const bf16x8*)&Kl[kf * 16 + fr][8 * g];
            const bf16x8 kh1 = *(const bf16x8*)&Kh[kf * 16 + fr][32 + 8 * g];
            const bf16x8 kl1 = *(const bf16x8*)&Kl[kf * 16 + fr][32 + 8 * g];
            s[kf] = __builtin_amdgcn_mfma_f32_16x16x32_bf16(kh0, qh0, s[kf], 0, 0, 0);
            s[kf] = __builtin_amdgcn_mfma_f32_16x16x32_bf16(kl0, qh0, s[kf], 0, 0, 0);
            s[kf] = __builtin_amdgcn_mfma_f32_16x16x32_bf16(kh0, ql0, s[kf], 0, 0, 0);
            s[kf] = __builtin_amdgcn_mfma_f32_16x16x32_bf16(kh1, qh1, s[kf], 0, 0, 0);
            s[kf] = __builtin_amdgcn_mfma_f32_16x16x32_bf16(kl1, qh1, s[kf], 0, 0, 0);
            s[kf] = __builtin_amdgcn_mfma_f32_16x16x32_bf16(kh1, ql1, s[kf], 0, 0, 0);
        }

        // ---- scale + causal mask + per-q max ----
        const bool dm = (kt * 64 + 63 > qw);
        float tmax = -1e30f;
        #pragma unroll
        for (int kf = 0; kf < 4; ++kf)
            #pragma unroll
            for (int j = 0; j < 4; ++j) {
                float v = s[kf][j] * 0.125f;
                if (dm && (kt * 64 + kf * 16 + 4 * g + j > qg)) v = -1e30f;
                s[kf][j] = v;
                tmax = fmaxf(tmax, v);
            }
        tmax = fmaxf(tmax, __shfl_xor(tmax, 16));
        tmax = fmaxf(tmax, __shfl_xor(tmax, 32));
        const float mn = fmaxf(mrun, tmax);
        const float sf = __expf(mrun - mn);
        mrun = mn;
        lrun *= sf;
        #pragma unroll
        for (int df = 0; df < 4; ++df)
            #pragma unroll
            for (int j = 0; j < 4; ++j) O[df][j] *= sf;

        // ---- P = exp(S-m), bf16 hi/lo; l from ROUNDED p ----
        #pragma unroll
        for (int kf = 0; kf < 4; ++kf) {
            uint hw0, hw1, lw0, lw1;
            {
                const float p0 = __expf(s[kf][0] - mn);
                const float p1 = __expf(s[kf][1] - mn);
                const float p2 = __expf(s[kf][2] - mn);
                const float p3 = __expf(s[kf][3] - mn);
                const ushort h0 = f2bf(p0), h1 = f2bf(p1), h2 = f2bf(p2), h3 = f2bf(p3);
                const ushort l0 = f2bf(p0 - bf2f(h0)), l1 = f2bf(p1 - bf2f(h1));
                const ushort l2 = f2bf(p2 - bf2f(h2)), l3 = f2bf(p3 - bf2f(h3));
                lrun += (bf2f(h0) + bf2f(l0)) + (bf2f(h1) + bf2f(l1))
                      + (bf2f(h2) + bf2f(l2)) + (bf2f(h3) + bf2f(l3));
                hw0 = (uint)h0 | ((uint)h1 << 16);
                hw1 = (uint)h2 | ((uint)h3 << 16);
                lw0 = (uint)l0 | ((uint)l1 << 16);
                lw1 = (uint)l2 | ((uint)l3 << 16);
            }
            const int kb = kf * 16 + 4 * g;
            *(uint*)&Pw[wave][0][fr][kb]     = hw0;
            *(uint*)&Pw[wave][0][fr][kb + 2] = hw1;
            *(uint*)&Pw[wave][1][fr][kb]     = lw0;
            *(uint*)&Pw[wave][1][fr][kb + 2] = lw1;
        }

        // ---- PV: O^T[d][q] += V^T x P  (2-term) ----
        #pragma unroll
        for (int c = 0; c < 2; ++c) {
            const bf16x8 pbh = *(const bf16x8*)&Pw[wave][0][fr][c * 32 + 8 * g];
            const bf16x8 pbl = *(const bf16x8*)&Pw[wave][1][fr][c * 32 + 8 * g];
            #pragma unroll
            for (int df = 0; df < 4; ++df) {
                const bf16x8 va = *(const bf16x8*)&Vs[df * 16 + fr][c * 32 + 8 * g];
                O[df] = __builtin_amdgcn_mfma_f32_16x16x32_bf16(va, pbh, O[df], 0, 0, 0);
                O[df] = __builtin_amdgcn_mfma_f32_16x16x32_bf16(va, pbl, O[df], 0, 0, 0);
            }
        }
    }

    // ---- finalize ----
    lrun += __shfl_xor(lrun, 16);
    lrun += __shfl_xor(lrun, 32);
    const float inv = 1.f / lrun;

    float* Ol = (float*)&Pw[wave][0][0][0];   // [16][68] f32 = 4352 B (fits 4608 B)
    #pragma unroll
    for (int df = 0; df < 4; ++df)
        #pragma unroll
        for (int j = 0; j < 4; ++j)
            Ol[fr * 68 + df * 16 + 4 * g + j] = O[df][j] * inv;

    const int q2 = lane >> 2;
    const int dl = (lane & 3) * 4;
    const size_t orow = ((size_t)(b * TSEQ + q0 + wave * 16 + q2)) * N_EMBD + h * HD;
    #pragma unroll
    for (int i = 0; i < 4; ++i) {
        const float4 y = *(const float4*)&Ol[q2 * 68 + dl + 16 * i];
        ushort4 o4;
        o4.x = f2bf(y.x); o4.y = f2bf(y.y); o4.z = f2bf(y.z); o4.w = f2bf(y.w);
        *(ushort4*)&ath[orow + dl + 16 * i] = o4;
    }
}

// ---------------------------------------------------------------------------
// Orchestration.  Workspace (184,549,376 B, unchanged layout):
// ---------------------------------------------------------------------------
extern "C" void kernel_launch(void* const* d_in, const int* in_sizes, int n_in,
                              void* d_out, int out_size, void* d_ws, size_t ws_size,
                              hipStream_t stream) {
    const float* x      = (const float*)d_in[0];
    const float* W_attn = (const float*)d_in[1];
    const float* b_attn = (const float*)d_in[2];
    const float* W_proj = (const float*)d_in[3];
    const float* b_proj = (const float*)d_in[4];
    float* out = (float*)d_out;
    (void)in_sizes; (void)n_in; (void)out_size; (void)ws_size;

    char* ws = (char*)d_ws;
    ushort* qkvh = (ushort*)ws; ws += (size_t)MROWS * 3 * N_EMBD * 2;
    ushort* qkvl = (ushort*)ws; ws += (size_t)MROWS * 3 * N_EMBD * 2;
    ushort* xh   = (ushort*)ws; ws += (size_t)MROWS * N_EMBD * 2;
    ushort* xl   = (ushort*)ws; ws += (size_t)MROWS * N_EMBD * 2;
    ushort* wah  = (ushort*)ws; ws += (size_t)3 * N_EMBD * N_EMBD * 2;
    ushort* wal  = (ushort*)ws; ws += (size_t)3 * N_EMBD * N_EMBD * 2;
    ushort* wph  = (ushort*)ws; ws += (size_t)N_EMBD * N_EMBD * 2;
    ushort* wpl  = (ushort*)ws; ws += (size_t)N_EMBD * N_EMBD * 2;
    ushort* vth  = (ushort*)ws; ws += (size_t)MROWS * N_EMBD * 2;
    ushort* ath  = (ushort*)ws;

    dim3 blk(256);

    split_bf16<<<dim3(MROWS * N_EMBD / 1024), blk, 0, stream>>>(x, xh, xl);
    transpose_split<<<dim3(3 * N_EMBD / 32, N_EMBD / 32), blk, 0, stream>>>(
        W_attn, wah, wal, N_EMBD, 3 * N_EMBD);
    transpose_split<<<dim3(N_EMBD / 32, N_EMBD / 32), blk, 0, stream>>>(
        W_proj, wph, wpl, N_EMBD, N_EMBD);

    // qkv = x @ W_attn + b_attn  -> bf16 hi/lo
    gemm_mfma<true, true><<<dim3(3 * N_EMBD / 128, MROWS / 128), blk, 0, stream>>>(
        xh, xl, wah, wal, b_attn, nullptr, qkvh, qkvl, MROWS, 3 * N_EMBD, N_EMBD);

    // V^T
    transpose_v<<<dim3(TSEQ / 64, N_HEAD, BSZ), blk, 0, stream>>>(qkvh, vth);

    // attention
    flash_attn_mfma<<<dim3(TSEQ / 128, N_HEAD, BSZ), dim3(512), 0, stream>>>(
        qkvh, qkvl, vth, ath);

    // out = attout @ W_proj + b_proj  (A hi-only, 2-term)
    gemm_mfma<false, false><<<dim3(N_EMBD / 128, MROWS / 128), blk, 0, stream>>>(
        ath, nullptr, wph, wpl, b_proj, out, nullptr, nullptr, MROWS, N_EMBD, N_EMBD);
}

// Round 5
// 545.672 us; speedup vs baseline: 1.8625x; 1.8625x over previous
//
#include <hip/hip_runtime.h>

// Problem constants (match reference)
#define N_EMBD 1024
#define N_HEAD 16
#define HD 64            // head dim
#define BSZ 4
#define TSEQ 2048
#define MROWS (BSZ * TSEQ)   // 8192

using bf16x8 = __attribute__((ext_vector_type(8))) short;
using f32x4  = __attribute__((ext_vector_type(4))) float;

// Raw-bit bf16 helpers (RN-even).
__device__ __forceinline__ ushort f2bf(float f) {
    uint u = __float_as_uint(f);
    u += 0x7FFFu + ((u >> 16) & 1u);
    return (ushort)(u >> 16);
}
__device__ __forceinline__ float bf2f(ushort h) {
    return __uint_as_float(((uint)h) << 16);
}

// Async global->LDS, 16 B per lane. LDS dest must be wave-uniform base
// (HW writes base + lane*16); global src is per-lane.
__device__ __forceinline__ void gload16(const ushort* g, short* l) {
    __builtin_amdgcn_global_load_lds(
        (const __attribute__((address_space(1))) void*)g,
        (__attribute__((address_space(3))) void*)l, 16, 0, 0);
}

// ---------------------------------------------------------------------------
// split_bf16: A (f32) -> H = bf16(A), L = bf16(A - H).  4 elems/thread.
// ---------------------------------------------------------------------------
__global__ __launch_bounds__(256) void split_bf16(const float* __restrict__ A,
                                                  ushort* __restrict__ H,
                                                  ushort* __restrict__ L)
{
    const size_t i = ((size_t)blockIdx.x * 256 + threadIdx.x) * 4;
    const float4 v = *(const float4*)&A[i];
    ushort4 h, l;
    h.x = f2bf(v.x); l.x = f2bf(v.x - bf2f(h.x));
    h.y = f2bf(v.y); l.y = f2bf(v.y - bf2f(h.y));
    h.z = f2bf(v.z); l.z = f2bf(v.z - bf2f(h.z));
    h.w = f2bf(v.w); l.w = f2bf(v.w - bf2f(h.w));
    *(ushort4*)&H[i] = h;
    *(ushort4*)&L[i] = l;
}

// ---------------------------------------------------------------------------
// transpose_split: W [K,N] f32 -> Th, Tl [N,K] bf16 (hi/lo split).
// ---------------------------------------------------------------------------
__global__ __launch_bounds__(256) void transpose_split(
    const float* __restrict__ W, ushort* __restrict__ Th, ushort* __restrict__ Tl,
    int K, int N)
{
    __shared__ float t[32][33];
    const int k0 = blockIdx.y * 32;
    const int n0 = blockIdx.x * 32;
    const int c = threadIdx.x & 31;
    const int r = threadIdx.x >> 5;   // 0..7
    #pragma unroll
    for (int i = 0; i < 4; ++i)
        t[r + i * 8][c] = W[(size_t)(k0 + r + i * 8) * N + n0 + c];
    __syncthreads();
    #pragma unroll
    for (int i = 0; i < 4; ++i) {
        const float v = t[c][r + i * 8];           // = W[k0+c][n0+r+i*8]
        const ushort hb = f2bf(v);
        const ushort lb = f2bf(v - bf2f(hb));
        const size_t o = (size_t)(n0 + r + i * 8) * K + k0 + c;
        Th[o] = hb;
        Tl[o] = lb;
    }
}

// ---------------------------------------------------------------------------
// transpose_v: qkvh v-part -> vth [b,h,d,t] bf16.  64x64 tiles via LDS.
// ---------------------------------------------------------------------------
__global__ __launch_bounds__(256) void transpose_v(
    const ushort* __restrict__ qkvh, ushort* __restrict__ vth)
{
    __shared__ __align__(16) ushort tr[64][72];
    const int t0 = blockIdx.x * 64;
    const int h  = blockIdx.y;
    const int b  = blockIdx.z;
    const int r  = threadIdx.x >> 2;         // 0..63
    const int c4 = (threadIdx.x & 3) * 16;   // 0,16,32,48

    const size_t inb = ((size_t)(b * TSEQ + t0 + r)) * (3 * N_EMBD) + 2 * N_EMBD + h * HD + c4;
    *(float4*)&tr[r][c4]     = *(const float4*)&qkvh[inb];
    *(float4*)&tr[r][c4 + 8] = *(const float4*)&qkvh[inb + 8];
    __syncthreads();

    ushort v[16] __attribute__((aligned(16)));
    #pragma unroll
    for (int u = 0; u < 16; ++u) v[u] = tr[c4 + u][r];   // = V[t0+c4+u][d=r]
    const size_t ob = (((size_t)(b * N_HEAD + h)) * HD + r) * TSEQ + t0 + c4;
    *(float4*)&vth[ob]     = ((const float4*)v)[0];
    *(float4*)&vth[ob + 8] = ((const float4*)v)[1];
}

// ---------------------------------------------------------------------------
// Split-bf16 MFMA GEMM, m97 structure.  C[M,N] = A[M,K] @ B^T[N,K] + bias.
// ASPLIT: 3-term (AhBh+AlBh+AhBl); else 2-term (AhBh+AhBl).
// OUTBF16: hi/lo bf16 planes; else f32.
// 128x128 tile, BK=32, 4 waves, 64x64/wave, 4x4 16x16x32 frags.
// Staging: global_load_lds width 16, LINEAR LDS planes [128][32] bf16
// (fragment ds_read_b128 footprint = contiguous 1024 B -> bank-balanced).
// Epilogue: LDS-staged coalesced stores, fits the same 32 KiB buffer.
// ---------------------------------------------------------------------------
template<bool ASPLIT, bool OUTBF16>
__global__ __launch_bounds__(256) void gemm_mfma(
    const ushort* __restrict__ Ah, const ushort* __restrict__ Al,
    const ushort* __restrict__ Bh, const ushort* __restrict__ Bl,
    const float* __restrict__ bias,
    float* __restrict__ Cf, ushort* __restrict__ Ch, ushort* __restrict__ Cl,
    int M, int N, int K)
{
    // K-loop: 4 planes x 128 rows x 32 bf16 (64 B/row) = 32768 B, linear.
    // epilogue bf16: 4 waves x 32 rows x 64 shorts = 32768 B
    // epilogue f32 : 4 waves x 32 rows x 64 f32    = 32768 B
    __shared__ __align__(16) short lds_raw[16384];

    const int tid  = threadIdx.x;
    const int wave = tid >> 6;
    const int lane = tid & 63;
    const int wr   = wave >> 1;
    const int wc   = wave & 1;
    const int row0 = blockIdx.y * 128;
    const int col0 = blockIdx.x * 128;

    // staging geometry: wave w issues 2 chunks/plane; chunk = 16 rows x 64 B.
    // lane l -> row chunk_row + (l>>2), cols (l&3)*8..+8 (elements).
    const int sr  = wave * 32 + (lane >> 2);     // row for issue 0 (+16 for issue 1)
    const int sco = (lane & 3) * 8;
    const ushort* gAh = Ah + (size_t)(row0 + sr) * K + sco;
    const ushort* gAl = ASPLIT ? (Al + (size_t)(row0 + sr) * K + sco) : nullptr;
    const ushort* gBh = Bh + (size_t)(col0 + sr) * K + sco;
    const ushort* gBl = Bl + (size_t)(col0 + sr) * K + sco;
    short* const ldst = lds_raw + wave * 1024;   // + plane*4096 + issue*512

    const int fr = lane & 15;
    const int fq = lane >> 4;
    const int ko = fq * 8;

    f32x4 acc[4][4] = {};

    for (int k0 = 0; k0 < K; k0 += 32) {
        const size_t K16 = (size_t)16 * K;
        gload16(gAh + k0,       ldst);
        gload16(gAh + k0 + K16, ldst + 512);
        if (ASPLIT) {
            gload16(gAl + k0,       ldst + 4096);
            gload16(gAl + k0 + K16, ldst + 4096 + 512);
        }
        gload16(gBh + k0,       ldst + 8192);
        gload16(gBh + k0 + K16, ldst + 8192 + 512);
        gload16(gBl + k0,       ldst + 12288);
        gload16(gBl + k0 + K16, ldst + 12288 + 512);
        __syncthreads();   // drains vmcnt -> staged tile visible

        bf16x8 a_h[4], a_l[4], b_h[4], b_l[4];
        #pragma unroll
        for (int m = 0; m < 4; ++m) {
            const int r = wr * 64 + m * 16 + fr;
            a_h[m] = *(const bf16x8*)&lds_raw[r * 32 + ko];
            if (ASPLIT) a_l[m] = *(const bf16x8*)&lds_raw[4096 + r * 32 + ko];
        }
        #pragma unroll
        for (int n = 0; n < 4; ++n) {
            const int r = wc * 64 + n * 16 + fr;
            b_h[n] = *(const bf16x8*)&lds_raw[8192 + r * 32 + ko];
            b_l[n] = *(const bf16x8*)&lds_raw[12288 + r * 32 + ko];
        }

        #pragma unroll
        for (int m = 0; m < 4; ++m)
            #pragma unroll
            for (int n = 0; n < 4; ++n) {
                acc[m][n] = __builtin_amdgcn_mfma_f32_16x16x32_bf16(a_h[m], b_h[n], acc[m][n], 0, 0, 0);
                if (ASPLIT)
                    acc[m][n] = __builtin_amdgcn_mfma_f32_16x16x32_bf16(a_l[m], b_h[n], acc[m][n], 0, 0, 0);
                acc[m][n] = __builtin_amdgcn_mfma_f32_16x16x32_bf16(a_h[m], b_l[n], acc[m][n], 0, 0, 0);
            }
        __syncthreads();   // frag reads done before next stage overwrites
    }

    // ---- epilogue: D col = lane&15, row = (lane>>4)*4 + j  [HW-verified] ----
    float bv[4];
    #pragma unroll
    for (int n = 0; n < 4; ++n) bv[n] = bias[col0 + wc * 64 + n * 16 + fr];

    if (OUTBF16) {
        short* wbuf = lds_raw + wave * 2048;     // 32 rows x 64 shorts (128 B)
        #pragma unroll
        for (int t = 0; t < 2; ++t) {
            ushort* dst = (t == 0) ? Ch : Cl;
            #pragma unroll
            for (int half = 0; half < 2; ++half) {
                __syncthreads();
                #pragma unroll
                for (int m2 = 0; m2 < 2; ++m2) {
                    const int m = half * 2 + m2;
                    #pragma unroll
                    for (int j = 0; j < 4; ++j)
                        #pragma unroll
                        for (int n = 0; n < 4; ++n) {
                            const float o = acc[m][n][j] + bv[n];
                            const ushort hb = f2bf(o);
                            wbuf[(m2 * 16 + fq * 4 + j) * 64 + n * 16 + fr] =
                                (short)(t == 0 ? hb : f2bf(o - bf2f(hb)));
                        }
                }
                __syncthreads();
                #pragma unroll
                for (int i = 0; i < 4; ++i) {
                    const int r = i * 8 + (lane >> 3);
                    const bf16x8 v = *(const bf16x8*)&wbuf[r * 64 + (lane & 7) * 8];
                    *(bf16x8*)&dst[(size_t)(row0 + wr * 64 + half * 32 + r) * N
                                   + col0 + wc * 64 + (lane & 7) * 8] = v;
                }
            }
        }
    } else {
        float* fbuf = (float*)lds_raw + wave * 2048;  // 32 rows x 64 f32 (256 B)
        #pragma unroll
        for (int half = 0; half < 2; ++half) {
            __syncthreads();
            #pragma unroll
            for (int m2 = 0; m2 < 2; ++m2) {
                const int m = half * 2 + m2;
                #pragma unroll
                for (int j = 0; j < 4; ++j)
                    #pragma unroll
                    for (int n = 0; n < 4; ++n)
                        fbuf[(m2 * 16 + fq * 4 + j) * 64 + n * 16 + fr] = acc[m][n][j] + bv[n];
            }
            __syncthreads();
            #pragma unroll
            for (int i = 0; i < 8; ++i) {
                const int r = i * 4 + (lane >> 4);
                const float4 v = *(const float4*)&fbuf[r * 64 + (lane & 15) * 4];
                *(float4*)&Cf[(size_t)(row0 + wr * 64 + half * 32 + r) * N
                              + col0 + wc * 64 + (lane & 15) * 4] = v;
            }
        }
    }
}

// ---------------------------------------------------------------------------
// MFMA flash attention (causal).  8 waves x 16 q-rows; KBLK 64.  (unchanged)
// ---------------------------------------------------------------------------
__global__ __launch_bounds__(512, 4) void flash_attn_mfma(
    const ushort* __restrict__ qkvh, const ushort* __restrict__ qkvl,
    const ushort* __restrict__ vth, ushort* __restrict__ ath)
{
    __shared__ __align__(16) short Kh[64][72];
    __shared__ __align__(16) short Kl[64][72];
    __shared__ __align__(16) short Vs[64][72];
    __shared__ __align__(16) short Pw[8][2][16][72];

    const int tid  = threadIdx.x;
    const int wave = tid >> 6;
    const int lane = tid & 63;
    const int fr = lane & 15;
    const int g  = lane >> 4;
    const int q0 = blockIdx.x * 128;
    const int h  = blockIdx.y;
    const int b  = blockIdx.z;
    const int qw = q0 + wave * 16;
    const int qg = qw + fr;

    const size_t qrow = ((size_t)(b * TSEQ + qg)) * (3 * N_EMBD) + h * HD + 8 * g;
    const bf16x8 qh0 = *(const bf16x8*)&qkvh[qrow];
    const bf16x8 qh1 = *(const bf16x8*)&qkvh[qrow + 32];
    const bf16x8 ql0 = *(const bf16x8*)&qkvl[qrow];
    const bf16x8 ql1 = *(const bf16x8*)&qkvl[qrow + 32];

    f32x4 O[4] = {};
    float mrun = -1e30f, lrun = 0.f;

    const int sr = tid >> 3;
    const int sc = (tid & 7) * 8;
    const ushort* kgh = qkvh + ((size_t)(b * TSEQ + sr)) * (3 * N_EMBD) + N_EMBD + h * HD + sc;
    const ushort* kgl = qkvl + ((size_t)(b * TSEQ + sr)) * (3 * N_EMBD) + N_EMBD + h * HD + sc;
    const ushort* vg  = vth + (((size_t)(b * N_HEAD + h)) * HD + sr) * TSEQ + sc;

    const int nt = q0 / 64 + 2;
    for (int kt = 0; kt < nt; ++kt) {
        const float4 rkh = *(const float4*)(kgh + (size_t)kt * 64 * 3 * N_EMBD);
        const float4 rkl = *(const float4*)(kgl + (size_t)kt * 64 * 3 * N_EMBD);
        const float4 rv  = *(const float4*)(vg + kt * 64);
        __syncthreads();
        *(float4*)&Kh[sr][sc] = rkh;
        *(float4*)&Kl[sr][sc] = rkl;
        *(float4*)&Vs[sr][sc] = rv;
        __syncthreads();

        if (kt * 64 > qw + 15) continue;

        f32x4 s[4] = {};
        #pragma unroll
        for (int kf = 0; kf < 4; ++kf) {
            const bf16x8 kh0 = *(const bf16x8*)&Kh[kf * 16 + fr][8 * g];
            const bf16x8 kl0 = *(const bf16x8*)&Kl[kf * 16 + fr][8 * g];
            const bf16x8 kh1 = *(const bf16x8*)&Kh[kf * 16 + fr][32 + 8 * g];
            const bf16x8 kl1 = *(const bf16x8*)&Kl[kf * 16 + fr][32 + 8 * g];
            s[kf] = __builtin_amdgcn_mfma_f32_16x16x32_bf16(kh0, qh0, s[kf], 0, 0, 0);
            s[kf] = __builtin_amdgcn_mfma_f32_16x16x32_bf16(kl0, qh0, s[kf], 0, 0, 0);
            s[kf] = __builtin_amdgcn_mfma_f32_16x16x32_bf16(kh0, ql0, s[kf], 0, 0, 0);
            s[kf] = __builtin_amdgcn_mfma_f32_16x16x32_bf16(kh1, qh1, s[kf], 0, 0, 0);
            s[kf] = __builtin_amdgcn_mfma_f32_16x16x32_bf16(kl1, qh1, s[kf], 0, 0, 0);
            s[kf] = __builtin_amdgcn_mfma_f32_16x16x32_bf16(kh1, ql1, s[kf], 0, 0, 0);
        }

        const bool dm = (kt * 64 + 63 > qw);
        float tmax = -1e30f;
        #pragma unroll
        for (int kf = 0; kf < 4; ++kf)
            #pragma unroll
            for (int j = 0; j < 4; ++j) {
                float v = s[kf][j] * 0.125f;
                if (dm && (kt * 64 + kf * 16 + 4 * g + j > qg)) v = -1e30f;
                s[kf][j] = v;
                tmax = fmaxf(tmax, v);
            }
        tmax = fmaxf(tmax, __shfl_xor(tmax, 16));
        tmax = fmaxf(tmax, __shfl_xor(tmax, 32));
        const float mn = fmaxf(mrun, tmax);
        const float sf = __expf(mrun - mn);
        mrun = mn;
        lrun *= sf;
        #pragma unroll
        for (int df = 0; df < 4; ++df)
            #pragma unroll
            for (int j = 0; j < 4; ++j) O[df][j] *= sf;

        #pragma unroll
        for (int kf = 0; kf < 4; ++kf) {
            uint hw0, hw1, lw0, lw1;
            {
                const float p0 = __expf(s[kf][0] - mn);
                const float p1 = __expf(s[kf][1] - mn);
                const float p2 = __expf(s[kf][2] - mn);
                const float p3 = __expf(s[kf][3] - mn);
                const ushort h0 = f2bf(p0), h1 = f2bf(p1), h2 = f2bf(p2), h3 = f2bf(p3);
                const ushort l0 = f2bf(p0 - bf2f(h0)), l1 = f2bf(p1 - bf2f(h1));
                const ushort l2 = f2bf(p2 - bf2f(h2)), l3 = f2bf(p3 - bf2f(h3));
                lrun += (bf2f(h0) + bf2f(l0)) + (bf2f(h1) + bf2f(l1))
                      + (bf2f(h2) + bf2f(l2)) + (bf2f(h3) + bf2f(l3));
                hw0 = (uint)h0 | ((uint)h1 << 16);
                hw1 = (uint)h2 | ((uint)h3 << 16);
                lw0 = (uint)l0 | ((uint)l1 << 16);
                lw1 = (uint)l2 | ((uint)l3 << 16);
            }
            const int kb = kf * 16 + 4 * g;
            *(uint*)&Pw[wave][0][fr][kb]     = hw0;
            *(uint*)&Pw[wave][0][fr][kb + 2] = hw1;
            *(uint*)&Pw[wave][1][fr][kb]     = lw0;
            *(uint*)&Pw[wave][1][fr][kb + 2] = lw1;
        }

        #pragma unroll
        for (int c = 0; c < 2; ++c) {
            const bf16x8 pbh = *(const bf16x8*)&Pw[wave][0][fr][c * 32 + 8 * g];
            const bf16x8 pbl = *(const bf16x8*)&Pw[wave][1][fr][c * 32 + 8 * g];
            #pragma unroll
            for (int df = 0; df < 4; ++df) {
                const bf16x8 va = *(const bf16x8*)&Vs[df * 16 + fr][c * 32 + 8 * g];
                O[df] = __builtin_amdgcn_mfma_f32_16x16x32_bf16(va, pbh, O[df], 0, 0, 0);
                O[df] = __builtin_amdgcn_mfma_f32_16x16x32_bf16(va, pbl, O[df], 0, 0, 0);
            }
        }
    }

    lrun += __shfl_xor(lrun, 16);
    lrun += __shfl_xor(lrun, 32);
    const float inv = 1.f / lrun;

    float* Ol = (float*)&Pw[wave][0][0][0];
    #pragma unroll
    for (int df = 0; df < 4; ++df)
        #pragma unroll
        for (int j = 0; j < 4; ++j)
            Ol[fr * 68 + df * 16 + 4 * g + j] = O[df][j] * inv;

    const int q2 = lane >> 2;
    const int dl = (lane & 3) * 4;
    const size_t orow = ((size_t)(b * TSEQ + q0 + wave * 16 + q2)) * N_EMBD + h * HD;
    #pragma unroll
    for (int i = 0; i < 4; ++i) {
        const float4 y = *(const float4*)&Ol[q2 * 68 + dl + 16 * i];
        ushort4 o4;
        o4.x = f2bf(y.x); o4.y = f2bf(y.y); o4.z = f2bf(y.z); o4.w = f2bf(y.w);
        *(ushort4*)&ath[orow + dl + 16 * i] = o4;
    }
}

// ---------------------------------------------------------------------------
// Orchestration.  Workspace (184,549,376 B, unchanged layout):
// ---------------------------------------------------------------------------
extern "C" void kernel_launch(void* const* d_in, const int* in_sizes, int n_in,
                              void* d_out, int out_size, void* d_ws, size_t ws_size,
                              hipStream_t stream) {
    const float* x      = (const float*)d_in[0];
    const float* W_attn = (const float*)d_in[1];
    const float* b_attn = (const float*)d_in[2];
    const float* W_proj = (const float*)d_in[3];
    const float* b_proj = (const float*)d_in[4];
    float* out = (float*)d_out;
    (void)in_sizes; (void)n_in; (void)out_size; (void)ws_size;

    char* ws = (char*)d_ws;
    ushort* qkvh = (ushort*)ws; ws += (size_t)MROWS * 3 * N_EMBD * 2;
    ushort* qkvl = (ushort*)ws; ws += (size_t)MROWS * 3 * N_EMBD * 2;
    ushort* xh   = (ushort*)ws; ws += (size_t)MROWS * N_EMBD * 2;
    ushort* xl   = (ushort*)ws; ws += (size_t)MROWS * N_EMBD * 2;
    ushort* wah  = (ushort*)ws; ws += (size_t)3 * N_EMBD * N_EMBD * 2;
    ushort* wal  = (ushort*)ws; ws += (size_t)3 * N_EMBD * N_EMBD * 2;
    ushort* wph  = (ushort*)ws; ws += (size_t)N_EMBD * N_EMBD * 2;
    ushort* wpl  = (ushort*)ws; ws += (size_t)N_EMBD * N_EMBD * 2;
    ushort* vth  = (ushort*)ws; ws += (size_t)MROWS * N_EMBD * 2;
    ushort* ath  = (ushort*)ws;

    dim3 blk(256);

    split_bf16<<<dim3(MROWS * N_EMBD / 1024), blk, 0, stream>>>(x, xh, xl);
    transpose_split<<<dim3(3 * N_EMBD / 32, N_EMBD / 32), blk, 0, stream>>>(
        W_attn, wah, wal, N_EMBD, 3 * N_EMBD);
    transpose_split<<<dim3(N_EMBD / 32, N_EMBD / 32), blk, 0, stream>>>(
        W_proj, wph, wpl, N_EMBD, N_EMBD);

    // qkv = x @ W_attn + b_attn  -> bf16 hi/lo
    gemm_mfma<true, true><<<dim3(3 * N_EMBD / 128, MROWS / 128), blk, 0, stream>>>(
        xh, xl, wah, wal, b_attn, nullptr, qkvh, qkvl, MROWS, 3 * N_EMBD, N_EMBD);

    // V^T
    transpose_v<<<dim3(TSEQ / 64, N_HEAD, BSZ), blk, 0, stream>>>(qkvh, vth);

    // attention
    flash_attn_mfma<<<dim3(TSEQ / 128, N_HEAD, BSZ), dim3(512), 0, stream>>>(
        qkvh, qkvl, vth, ath);

    // out = attout @ W_proj + b_proj  (A hi-only, 2-term)
    gemm_mfma<false, false><<<dim3(N_EMBD / 128, MROWS / 128), blk, 0, stream>>>(
        ath, nullptr, wph, wpl, b_proj, out, nullptr, nullptr, MROWS, N_EMBD, N_EMBD);
}

// Round 7
// 515.762 us; speedup vs baseline: 1.9705x; 1.0580x over previous
//
#include <hip/hip_runtime.h>

// Problem constants (match reference)
#define N_EMBD 1024
#define N_HEAD 16
#define HD 64            // head dim
#define BSZ 4
#define TSEQ 2048
#define MROWS (BSZ * TSEQ)   // 8192

using bf16x8 = __attribute__((ext_vector_type(8))) short;
using f32x4  = __attribute__((ext_vector_type(4))) float;

// Raw-bit bf16 helpers (RN-even).
__device__ __forceinline__ ushort f2bf(float f) {
    uint u = __float_as_uint(f);
    u += 0x7FFFu + ((u >> 16) & 1u);
    return (ushort)(u >> 16);
}
__device__ __forceinline__ float bf2f(ushort h) {
    return __uint_as_float(((uint)h) << 16);
}

// Async global->LDS, 16 B per lane. LDS dest must be wave-uniform base
// (HW writes base + lane*16); global src is per-lane.
__device__ __forceinline__ void gload16(const ushort* g, short* l) {
    __builtin_amdgcn_global_load_lds(
        (const __attribute__((address_space(1))) void*)g,
        (__attribute__((address_space(3))) void*)l, 16, 0, 0);
}

// ---------------------------------------------------------------------------
// split_bf16: A (f32) -> H = bf16(A), L = bf16(A - H).  4 elems/thread.
// ---------------------------------------------------------------------------
__global__ __launch_bounds__(256) void split_bf16(const float* __restrict__ A,
                                                  ushort* __restrict__ H,
                                                  ushort* __restrict__ L)
{
    const size_t i = ((size_t)blockIdx.x * 256 + threadIdx.x) * 4;
    const float4 v = *(const float4*)&A[i];
    ushort4 h, l;
    h.x = f2bf(v.x); l.x = f2bf(v.x - bf2f(h.x));
    h.y = f2bf(v.y); l.y = f2bf(v.y - bf2f(h.y));
    h.z = f2bf(v.z); l.z = f2bf(v.z - bf2f(h.z));
    h.w = f2bf(v.w); l.w = f2bf(v.w - bf2f(h.w));
    *(ushort4*)&H[i] = h;
    *(ushort4*)&L[i] = l;
}

// ---------------------------------------------------------------------------
// transpose_split: W [K,N] f32 -> Th, Tl [N,K] bf16 (hi/lo split).
// ---------------------------------------------------------------------------
__global__ __launch_bounds__(256) void transpose_split(
    const float* __restrict__ W, ushort* __restrict__ Th, ushort* __restrict__ Tl,
    int K, int N)
{
    __shared__ float t[32][33];
    const int k0 = blockIdx.y * 32;
    const int n0 = blockIdx.x * 32;
    const int c = threadIdx.x & 31;
    const int r = threadIdx.x >> 5;   // 0..7
    #pragma unroll
    for (int i = 0; i < 4; ++i)
        t[r + i * 8][c] = W[(size_t)(k0 + r + i * 8) * N + n0 + c];
    __syncthreads();
    #pragma unroll
    for (int i = 0; i < 4; ++i) {
        const float v = t[c][r + i * 8];           // = W[k0+c][n0+r+i*8]
        const ushort hb = f2bf(v);
        const ushort lb = f2bf(v - bf2f(hb));
        const size_t o = (size_t)(n0 + r + i * 8) * K + k0 + c;
        Th[o] = hb;
        Tl[o] = lb;
    }
}

// ---------------------------------------------------------------------------
// transpose_v: qkvh v-part -> vth [b,h,d,t] bf16.  64x64 tiles via LDS.
// ---------------------------------------------------------------------------
__global__ __launch_bounds__(256) void transpose_v(
    const ushort* __restrict__ qkvh, ushort* __restrict__ vth)
{
    __shared__ __align__(16) ushort tr[64][72];
    const int t0 = blockIdx.x * 64;
    const int h  = blockIdx.y;
    const int b  = blockIdx.z;
    const int r  = threadIdx.x >> 2;         // 0..63
    const int c4 = (threadIdx.x & 3) * 16;   // 0,16,32,48

    const size_t inb = ((size_t)(b * TSEQ + t0 + r)) * (3 * N_EMBD) + 2 * N_EMBD + h * HD + c4;
    *(float4*)&tr[r][c4]     = *(const float4*)&qkvh[inb];
    *(float4*)&tr[r][c4 + 8] = *(const float4*)&qkvh[inb + 8];
    __syncthreads();

    ushort v[16] __attribute__((aligned(16)));
    #pragma unroll
    for (int u = 0; u < 16; ++u) v[u] = tr[c4 + u][r];   // = V[t0+c4+u][d=r]
    const size_t ob = (((size_t)(b * N_HEAD + h)) * HD + r) * TSEQ + t0 + c4;
    *(float4*)&vth[ob]     = ((const float4*)v)[0];
    *(float4*)&vth[ob + 8] = ((const float4*)v)[1];
}

// ---------------------------------------------------------------------------
// Split-bf16 MFMA GEMM, m97 structure (unchanged from round 5).
// ---------------------------------------------------------------------------
template<bool ASPLIT, bool OUTBF16>
__global__ __launch_bounds__(256) void gemm_mfma(
    const ushort* __restrict__ Ah, const ushort* __restrict__ Al,
    const ushort* __restrict__ Bh, const ushort* __restrict__ Bl,
    const float* __restrict__ bias,
    float* __restrict__ Cf, ushort* __restrict__ Ch, ushort* __restrict__ Cl,
    int M, int N, int K)
{
    __shared__ __align__(16) short lds_raw[16384];

    const int tid  = threadIdx.x;
    const int wave = tid >> 6;
    const int lane = tid & 63;
    const int wr   = wave >> 1;
    const int wc   = wave & 1;
    const int row0 = blockIdx.y * 128;
    const int col0 = blockIdx.x * 128;

    const int sr  = wave * 32 + (lane >> 2);
    const int sco = (lane & 3) * 8;
    const ushort* gAh = Ah + (size_t)(row0 + sr) * K + sco;
    const ushort* gAl = ASPLIT ? (Al + (size_t)(row0 + sr) * K + sco) : nullptr;
    const ushort* gBh = Bh + (size_t)(col0 + sr) * K + sco;
    const ushort* gBl = Bl + (size_t)(col0 + sr) * K + sco;
    short* const ldst = lds_raw + wave * 1024;

    const int fr = lane & 15;
    const int fq = lane >> 4;
    const int ko = fq * 8;

    f32x4 acc[4][4] = {};

    for (int k0 = 0; k0 < K; k0 += 32) {
        const size_t K16 = (size_t)16 * K;
        gload16(gAh + k0,       ldst);
        gload16(gAh + k0 + K16, ldst + 512);
        if (ASPLIT) {
            gload16(gAl + k0,       ldst + 4096);
            gload16(gAl + k0 + K16, ldst + 4096 + 512);
        }
        gload16(gBh + k0,       ldst + 8192);
        gload16(gBh + k0 + K16, ldst + 8192 + 512);
        gload16(gBl + k0,       ldst + 12288);
        gload16(gBl + k0 + K16, ldst + 12288 + 512);
        __syncthreads();

        bf16x8 a_h[4], a_l[4], b_h[4], b_l[4];
        #pragma unroll
        for (int m = 0; m < 4; ++m) {
            const int r = wr * 64 + m * 16 + fr;
            a_h[m] = *(const bf16x8*)&lds_raw[r * 32 + ko];
            if (ASPLIT) a_l[m] = *(const bf16x8*)&lds_raw[4096 + r * 32 + ko];
        }
        #pragma unroll
        for (int n = 0; n < 4; ++n) {
            const int r = wc * 64 + n * 16 + fr;
            b_h[n] = *(const bf16x8*)&lds_raw[8192 + r * 32 + ko];
            b_l[n] = *(const bf16x8*)&lds_raw[12288 + r * 32 + ko];
        }

        #pragma unroll
        for (int m = 0; m < 4; ++m)
            #pragma unroll
            for (int n = 0; n < 4; ++n) {
                acc[m][n] = __builtin_amdgcn_mfma_f32_16x16x32_bf16(a_h[m], b_h[n], acc[m][n], 0, 0, 0);
                if (ASPLIT)
                    acc[m][n] = __builtin_amdgcn_mfma_f32_16x16x32_bf16(a_l[m], b_h[n], acc[m][n], 0, 0, 0);
                acc[m][n] = __builtin_amdgcn_mfma_f32_16x16x32_bf16(a_h[m], b_l[n], acc[m][n], 0, 0, 0);
            }
        __syncthreads();
    }

    float bv[4];
    #pragma unroll
    for (int n = 0; n < 4; ++n) bv[n] = bias[col0 + wc * 64 + n * 16 + fr];

    if (OUTBF16) {
        short* wbuf = lds_raw + wave * 2048;
        #pragma unroll
        for (int t = 0; t < 2; ++t) {
            ushort* dst = (t == 0) ? Ch : Cl;
            #pragma unroll
            for (int half = 0; half < 2; ++half) {
                __syncthreads();
                #pragma unroll
                for (int m2 = 0; m2 < 2; ++m2) {
                    const int m = half * 2 + m2;
                    #pragma unroll
                    for (int j = 0; j < 4; ++j)
                        #pragma unroll
                        for (int n = 0; n < 4; ++n) {
                            const float o = acc[m][n][j] + bv[n];
                            const ushort hb = f2bf(o);
                            wbuf[(m2 * 16 + fq * 4 + j) * 64 + n * 16 + fr] =
                                (short)(t == 0 ? hb : f2bf(o - bf2f(hb)));
                        }
                }
                __syncthreads();
                #pragma unroll
                for (int i = 0; i < 4; ++i) {
                    const int r = i * 8 + (lane >> 3);
                    const bf16x8 v = *(const bf16x8*)&wbuf[r * 64 + (lane & 7) * 8];
                    *(bf16x8*)&dst[(size_t)(row0 + wr * 64 + half * 32 + r) * N
                                   + col0 + wc * 64 + (lane & 7) * 8] = v;
                }
            }
        }
    } else {
        float* fbuf = (float*)lds_raw + wave * 2048;
        #pragma unroll
        for (int half = 0; half < 2; ++half) {
            __syncthreads();
            #pragma unroll
            for (int m2 = 0; m2 < 2; ++m2) {
                const int m = half * 2 + m2;
                #pragma unroll
                for (int j = 0; j < 4; ++j)
                    #pragma unroll
                    for (int n = 0; n < 4; ++n)
                        fbuf[(m2 * 16 + fq * 4 + j) * 64 + n * 16 + fr] = acc[m][n][j] + bv[n];
            }
            __syncthreads();
            #pragma unroll
            for (int i = 0; i < 8; ++i) {
                const int r = i * 4 + (lane >> 4);
                const float4 v = *(const float4*)&fbuf[r * 64 + (lane & 15) * 4];
                *(float4*)&Cf[(size_t)(row0 + wr * 64 + half * 32 + r) * N
                              + col0 + wc * 64 + (lane & 15) * 4] = v;
            }
        }
    }
}

// ---------------------------------------------------------------------------
// MFMA flash attention (causal).  8 waves x 16 q-rows; KBLK 64.
//  * K/V LDS: linear [64][64] + XOR swizzle unit^=(row&7) on store AND read
//    (global addresses unchanged) -> even bank distribution on frag reads.
//  * Prefetch: tile t+1 global loads issued right after store-barrier of t,
//    latency hides under compute(t)  [T14].
//  * s_setprio(1) around MFMA clusters  [T5].
// ---------------------------------------------------------------------------
__global__ __launch_bounds__(512, 4) void flash_attn_mfma(
    const ushort* __restrict__ qkvh, const ushort* __restrict__ qkvl,
    const ushort* __restrict__ vth, ushort* __restrict__ ath)
{
    __shared__ __align__(16) short Kh[64][64];          // 8 KB, swizzled cols
    __shared__ __align__(16) short Kl[64][64];          // 8 KB
    __shared__ __align__(16) short Vs[64][64];          // 8 KB  [d][k_local]
    __shared__ __align__(16) short Pw[8][2][16][72];    // 36 KB [wave][hi/lo][q][k]

    const int tid  = threadIdx.x;
    const int wave = tid >> 6;
    const int lane = tid & 63;
    const int fr = lane & 15;
    const int g  = lane >> 4;
    const int q0 = blockIdx.x * 128;
    const int h  = blockIdx.y;
    const int b  = blockIdx.z;
    const int qw = q0 + wave * 16;
    const int qg = qw + fr;

    const size_t qrow = ((size_t)(b * TSEQ + qg)) * (3 * N_EMBD) + h * HD + 8 * g;
    const bf16x8 qh0 = *(const bf16x8*)&qkvh[qrow];
    const bf16x8 qh1 = *(const bf16x8*)&qkvh[qrow + 32];
    const bf16x8 ql0 = *(const bf16x8*)&qkvl[qrow];
    const bf16x8 ql1 = *(const bf16x8*)&qkvl[qrow + 32];

    f32x4 O[4] = {};
    float mrun = -1e30f, lrun = 0.f;

    // staging: row sr = tid>>3, logical unit u = tid&7 (16 B); store at
    // swizzled physical unit u^(sr&7). Global src address unchanged.
    const int sr  = tid >> 3;
    const int su  = tid & 7;
    const int spu = (su ^ (sr & 7)) * 8;         // physical short offset
    const int sc  = su * 8;
    const ushort* kgh = qkvh + ((size_t)(b * TSEQ + sr)) * (3 * N_EMBD) + N_EMBD + h * HD + sc;
    const ushort* kgl = qkvl + ((size_t)(b * TSEQ + sr)) * (3 * N_EMBD) + N_EMBD + h * HD + sc;
    const ushort* vg  = vth + (((size_t)(b * N_HEAD + h)) * HD + sr) * TSEQ + sc;

    // swizzled read units (per lane, constant)
    const int x7  = fr & 7;
    const int ru0 = (g ^ x7) * 8;            // K/V logical unit g   (d 0..31 half)
    const int ru1 = ((4 + g) ^ x7) * 8;      // K/V logical unit 4+g (d 32..63 half)

    const int nt = q0 / 64 + 2;

    // prologue: tile-0 loads in flight
    float4 nkh = *(const float4*)(kgh);
    float4 nkl = *(const float4*)(kgl);
    float4 nv  = *(const float4*)(vg);

    for (int kt = 0; kt < nt; ++kt) {
        __syncthreads();                 // prior tile's LDS reads done
        *(float4*)&Kh[sr][spu] = nkh;
        *(float4*)&Kl[sr][spu] = nkl;
        *(float4*)&Vs[sr][spu] = nv;
        __syncthreads();                 // tile visible

        if (kt + 1 < nt) {               // prefetch next tile (hides HBM lat)
            nkh = *(const float4*)(kgh + (size_t)(kt + 1) * 64 * 3 * N_EMBD);
            nkl = *(const float4*)(kgl + (size_t)(kt + 1) * 64 * 3 * N_EMBD);
            nv  = *(const float4*)(vg + (kt + 1) * 64);
        }

        if (kt * 64 > qw + 15) continue;     // fully masked for this wave

        // ---- QK^T: S^T[k][q], frag kf covers k_local = kf*16 + 4g + j ----
        f32x4 s[4] = {};
        __builtin_amdgcn_s_setprio(1);
        #pragma unroll
        for (int kf = 0; kf < 4; ++kf) {
            const int kr = kf * 16 + fr;
            const bf16x8 kh0 = *(const bf16x8*)&Kh[kr][ru0];
            const bf16x8 kl0 = *(const bf16x8*)&Kl[kr][ru0];
            const bf16x8 kh1 = *(const bf16x8*)&Kh[kr][ru1];
            const bf16x8 kl1 = *(const bf16x8*)&Kl[kr][ru1];
            s[kf] = __builtin_amdgcn_mfma_f32_16x16x32_bf16(kh0, qh0, s[kf], 0, 0, 0);
            s[kf] = __builtin_amdgcn_mfma_f32_16x16x32_bf16(kl0, qh0, s[kf], 0, 0, 0);
            s[kf] = __builtin_amdgcn_mfma_f32_16x16x32_bf16(kh0, ql0, s[kf], 0, 0, 0);
            s[kf] = __builtin_amdgcn_mfma_f32_16x16x32_bf16(kh1, qh1, s[kf], 0, 0, 0);
            s[kf] = __builtin_amdgcn_mfma_f32_16x16x32_bf16(kl1, qh1, s[kf], 0, 0, 0);
            s[kf] = __builtin_amdgcn_mfma_f32_16x16x32_bf16(kh1, ql1, s[kf], 0, 0, 0);
        }
        __builtin_amdgcn_s_setprio(0);

        // ---- scale + causal mask + per-q max ----
        const bool dm = (kt * 64 + 63 > qw);
        float tmax = -1e30f;
        #pragma unroll
        for (int kf = 0; kf < 4; ++kf)
            #pragma unroll
            for (int j = 0; j < 4; ++j) {
                float v = s[kf][j] * 0.125f;
                if (dm && (kt * 64 + kf * 16 + 4 * g + j > qg)) v = -1e30f;
                s[kf][j] = v;
                tmax = fmaxf(tmax, v);
            }
        tmax = fmaxf(tmax, __shfl_xor(tmax, 16));
        tmax = fmaxf(tmax, __shfl_xor(tmax, 32));
        const float mn = fmaxf(mrun, tmax);
        const float sf = __expf(mrun - mn);
        mrun = mn;
        lrun *= sf;
        #pragma unroll
        for (int df = 0; df < 4; ++df)
            #pragma unroll
            for (int j = 0; j < 4; ++j) O[df][j] *= sf;

        // ---- P = exp(S-m), bf16 hi/lo; l from ROUNDED p ----
        #pragma unroll
        for (int kf = 0; kf < 4; ++kf) {
            uint hw0, hw1, lw0, lw1;
            {
                const float p0 = __expf(s[kf][0] - mn);
                const float p1 = __expf(s[kf][1] - mn);
                const float p2 = __expf(s[kf][2] - mn);
                const float p3 = __expf(s[kf][3] - mn);
                const ushort h0 = f2bf(p0), h1 = f2bf(p1), h2 = f2bf(p2), h3 = f2bf(p3);
                const ushort l0 = f2bf(p0 - bf2f(h0)), l1 = f2bf(p1 - bf2f(h1));
                const ushort l2 = f2bf(p2 - bf2f(h2)), l3 = f2bf(p3 - bf2f(h3));
                lrun += (bf2f(h0) + bf2f(l0)) + (bf2f(h1) + bf2f(l1))
                      + (bf2f(h2) + bf2f(l2)) + (bf2f(h3) + bf2f(l3));
                hw0 = (uint)h0 | ((uint)h1 << 16);
                hw1 = (uint)h2 | ((uint)h3 << 16);
                lw0 = (uint)l0 | ((uint)l1 << 16);
                lw1 = (uint)l2 | ((uint)l3 << 16);
            }
            const int kb = kf * 16 + 4 * g;
            *(uint*)&Pw[wave][0][fr][kb]     = hw0;
            *(uint*)&Pw[wave][0][fr][kb + 2] = hw1;
            *(uint*)&Pw[wave][1][fr][kb]     = lw0;
            *(uint*)&Pw[wave][1][fr][kb + 2] = lw1;
        }

        // ---- PV: O^T[d][q] += V^T x P  (2-term) ----
        #pragma unroll
        for (int c = 0; c < 2; ++c) {
            const bf16x8 pbh = *(const bf16x8*)&Pw[wave][0][fr][c * 32 + 8 * g];
            const bf16x8 pbl = *(const bf16x8*)&Pw[wave][1][fr][c * 32 + 8 * g];
            const int rvc = ((4 * c + g) ^ x7) * 8;   // swizzled V unit
            __builtin_amdgcn_s_setprio(1);
            #pragma unroll
            for (int df = 0; df < 4; ++df) {
                const bf16x8 va = *(const bf16x8*)&Vs[df * 16 + fr][rvc];
                O[df] = __builtin_amdgcn_mfma_f32_16x16x32_bf16(va, pbh, O[df], 0, 0, 0);
                O[df] = __builtin_amdgcn_mfma_f32_16x16x32_bf16(va, pbl, O[df], 0, 0, 0);
            }
            __builtin_amdgcn_s_setprio(0);
        }
    }

    // ---- finalize ----
    lrun += __shfl_xor(lrun, 16);
    lrun += __shfl_xor(lrun, 32);
    const float inv = 1.f / lrun;

    float* Ol = (float*)&Pw[wave][0][0][0];   // [16][68] f32 (fits 4608 B)
    #pragma unroll
    for (int df = 0; df < 4; ++df)
        #pragma unroll
        for (int j = 0; j < 4; ++j)
            Ol[fr * 68 + df * 16 + 4 * g + j] = O[df][j] * inv;

    const int q2 = lane >> 2;
    const int dl = (lane & 3) * 4;
    const size_t orow = ((size_t)(b * TSEQ + q0 + wave * 16 + q2)) * N_EMBD + h * HD;
    #pragma unroll
    for (int i = 0; i < 4; ++i) {
        const float4 y = *(const float4*)&Ol[q2 * 68 + dl + 16 * i];
        ushort4 o4;
        o4.x = f2bf(y.x); o4.y = f2bf(y.y); o4.z = f2bf(y.z); o4.w = f2bf(y.w);
        *(ushort4*)&ath[orow + dl + 16 * i] = o4;
    }
}

// ---------------------------------------------------------------------------
// Orchestration.  Workspace (184,549,376 B, unchanged layout):
// ---------------------------------------------------------------------------
extern "C" void kernel_launch(void* const* d_in, const int* in_sizes, int n_in,
                              void* d_out, int out_size, void* d_ws, size_t ws_size,
                              hipStream_t stream) {
    const float* x      = (const float*)d_in[0];
    const float* W_attn = (const float*)d_in[1];
    const float* b_attn = (const float*)d_in[2];
    const float* W_proj = (const float*)d_in[3];
    const float* b_proj = (const float*)d_in[4];
    float* out = (float*)d_out;
    (void)in_sizes; (void)n_in; (void)out_size; (void)ws_size;

    char* ws = (char*)d_ws;
    ushort* qkvh = (ushort*)ws; ws += (size_t)MROWS * 3 * N_EMBD * 2;
    ushort* qkvl = (ushort*)ws; ws += (size_t)MROWS * 3 * N_EMBD * 2;
    ushort* xh   = (ushort*)ws; ws += (size_t)MROWS * N_EMBD * 2;
    ushort* xl   = (ushort*)ws; ws += (size_t)MROWS * N_EMBD * 2;
    ushort* wah  = (ushort*)ws; ws += (size_t)3 * N_EMBD * N_EMBD * 2;
    ushort* wal  = (ushort*)ws; ws += (size_t)3 * N_EMBD * N_EMBD * 2;
    ushort* wph  = (ushort*)ws; ws += (size_t)N_EMBD * N_EMBD * 2;
    ushort* wpl  = (ushort*)ws; ws += (size_t)N_EMBD * N_EMBD * 2;
    ushort* vth  = (ushort*)ws; ws += (size_t)MROWS * N_EMBD * 2;
    ushort* ath  = (ushort*)ws;

    dim3 blk(256);

    split_bf16<<<dim3(MROWS * N_EMBD / 1024), blk, 0, stream>>>(x, xh, xl);
    transpose_split<<<dim3(3 * N_EMBD / 32, N_EMBD / 32), blk, 0, stream>>>(
        W_attn, wah, wal, N_EMBD, 3 * N_EMBD);
    transpose_split<<<dim3(N_EMBD / 32, N_EMBD / 32), blk, 0, stream>>>(
        W_proj, wph, wpl, N_EMBD, N_EMBD);

    // qkv = x @ W_attn + b_attn  -> bf16 hi/lo
    gemm_mfma<true, true><<<dim3(3 * N_EMBD / 128, MROWS / 128), blk, 0, stream>>>(
        xh, xl, wah, wal, b_attn, nullptr, qkvh, qkvl, MROWS, 3 * N_EMBD, N_EMBD);

    // V^T
    transpose_v<<<dim3(TSEQ / 64, N_HEAD, BSZ), blk, 0, stream>>>(qkvh, vth);

    // attention
    flash_attn_mfma<<<dim3(TSEQ / 128, N_HEAD, BSZ), dim3(512), 0, stream>>>(
        qkvh, qkvl, vth, ath);

    // out = attout @ W_proj + b_proj  (A hi-only, 2-term)
    gemm_mfma<false, false><<<dim3(N_EMBD / 128, MROWS / 128), blk, 0, stream>>>(
        ath, nullptr, wph, wpl, b_proj, out, nullptr, nullptr, MROWS, N_EMBD, N_EMBD);
}

// Round 8
// 465.268 us; speedup vs baseline: 2.1844x; 1.1085x over previous
//
#include <hip/hip_runtime.h>

// Problem constants (match reference)
#define N_EMBD 1024
#define N_HEAD 16
#define HD 64            // head dim
#define BSZ 4
#define TSEQ 2048
#define MROWS (BSZ * TSEQ)   // 8192

// 0.125 (1/sqrt(hd)) / ln2  -> QK^T scores come out in log2 domain
#define QSCALE 0.1803368801111204f

using bf16x8 = __attribute__((ext_vector_type(8))) short;
using f32x4  = __attribute__((ext_vector_type(4))) float;

// Raw-bit bf16 helpers (RN-even).
__device__ __forceinline__ ushort f2bf(float f) {
    uint u = __float_as_uint(f);
    u += 0x7FFFu + ((u >> 16) & 1u);
    return (ushort)(u >> 16);
}
__device__ __forceinline__ float bf2f(ushort h) {
    return __uint_as_float(((uint)h) << 16);
}
__device__ __forceinline__ float fexp2(float x) {
#if __has_builtin(__builtin_amdgcn_exp2f)
    return __builtin_amdgcn_exp2f(x);
#else
    return exp2f(x);
#endif
}

// Async global->LDS, 16 B per lane.
__device__ __forceinline__ void gload16(const ushort* g, short* l) {
    __builtin_amdgcn_global_load_lds(
        (const __attribute__((address_space(1))) void*)g,
        (__attribute__((address_space(3))) void*)l, 16, 0, 0);
}

// ---------------------------------------------------------------------------
// split_bf16: A (f32) -> H = bf16(A), L = bf16(A - H).  4 elems/thread.
// ---------------------------------------------------------------------------
__global__ __launch_bounds__(256) void split_bf16(const float* __restrict__ A,
                                                  ushort* __restrict__ H,
                                                  ushort* __restrict__ L)
{
    const size_t i = ((size_t)blockIdx.x * 256 + threadIdx.x) * 4;
    const float4 v = *(const float4*)&A[i];
    ushort4 h, l;
    h.x = f2bf(v.x); l.x = f2bf(v.x - bf2f(h.x));
    h.y = f2bf(v.y); l.y = f2bf(v.y - bf2f(h.y));
    h.z = f2bf(v.z); l.z = f2bf(v.z - bf2f(h.z));
    h.w = f2bf(v.w); l.w = f2bf(v.w - bf2f(h.w));
    *(ushort4*)&H[i] = h;
    *(ushort4*)&L[i] = l;
}

// ---------------------------------------------------------------------------
// transpose_split: W [K,N] f32 -> Th, Tl [N,K] bf16 (hi/lo split).
// Output rows n < scaled_rows are multiplied by rowscale (q-column folding).
// ---------------------------------------------------------------------------
__global__ __launch_bounds__(256) void transpose_split(
    const float* __restrict__ W, ushort* __restrict__ Th, ushort* __restrict__ Tl,
    int K, int N, int scaled_rows, float rowscale)
{
    __shared__ float t[32][33];
    const int k0 = blockIdx.y * 32;
    const int n0 = blockIdx.x * 32;
    const int c = threadIdx.x & 31;
    const int r = threadIdx.x >> 5;   // 0..7
    #pragma unroll
    for (int i = 0; i < 4; ++i)
        t[r + i * 8][c] = W[(size_t)(k0 + r + i * 8) * N + n0 + c];
    __syncthreads();
    #pragma unroll
    for (int i = 0; i < 4; ++i) {
        const int n = n0 + r + i * 8;
        float v = t[c][r + i * 8];           // = W[k0+c][n]
        if (n < scaled_rows) v *= rowscale;
        const ushort hb = f2bf(v);
        const ushort lb = f2bf(v - bf2f(hb));
        const size_t o = (size_t)n * K + k0 + c;
        Th[o] = hb;
        Tl[o] = lb;
    }
}

// ---------------------------------------------------------------------------
// transpose_v: qkvh v-part -> vth [b,h,d,t] bf16.  64x64 tiles via LDS.
// ---------------------------------------------------------------------------
__global__ __launch_bounds__(256) void transpose_v(
    const ushort* __restrict__ qkvh, ushort* __restrict__ vth)
{
    __shared__ __align__(16) ushort tr[64][72];
    const int t0 = blockIdx.x * 64;
    const int h  = blockIdx.y;
    const int b  = blockIdx.z;
    const int r  = threadIdx.x >> 2;         // 0..63
    const int c4 = (threadIdx.x & 3) * 16;   // 0,16,32,48

    const size_t inb = ((size_t)(b * TSEQ + t0 + r)) * (3 * N_EMBD) + 2 * N_EMBD + h * HD + c4;
    *(float4*)&tr[r][c4]     = *(const float4*)&qkvh[inb];
    *(float4*)&tr[r][c4 + 8] = *(const float4*)&qkvh[inb + 8];
    __syncthreads();

    ushort v[16] __attribute__((aligned(16)));
    #pragma unroll
    for (int u = 0; u < 16; ++u) v[u] = tr[c4 + u][r];   // = V[t0+c4+u][d=r]
    const size_t ob = (((size_t)(b * N_HEAD + h)) * HD + r) * TSEQ + t0 + c4;
    *(float4*)&vth[ob]     = ((const float4*)v)[0];
    *(float4*)&vth[ob + 8] = ((const float4*)v)[1];
}

// ---------------------------------------------------------------------------
// Split-bf16 MFMA GEMM, m97 structure + XCD-aware block swizzle (T1).
// Bias cols < qcols are scaled by QSCALE (fold of softmax scale into q).
// ---------------------------------------------------------------------------
template<bool ASPLIT, bool OUTBF16>
__global__ __launch_bounds__(256) void gemm_mfma(
    const ushort* __restrict__ Ah, const ushort* __restrict__ Al,
    const ushort* __restrict__ Bh, const ushort* __restrict__ Bl,
    const float* __restrict__ bias,
    float* __restrict__ Cf, ushort* __restrict__ Ch, ushort* __restrict__ Cl,
    int M, int N, int K, int qcols)
{
    __shared__ __align__(16) short lds_raw[16384];

    // XCD swizzle (nwg % 8 == 0 for all our grids -> simple bijective form)
    const uint flat = blockIdx.y * gridDim.x + blockIdx.x;
    const uint nwg  = gridDim.x * gridDim.y;
    const uint swz  = (flat & 7) * (nwg >> 3) + (flat >> 3);
    const int  bx   = swz % gridDim.x;
    const int  by   = swz / gridDim.x;

    const int tid  = threadIdx.x;
    const int wave = tid >> 6;
    const int lane = tid & 63;
    const int wr   = wave >> 1;
    const int wc   = wave & 1;
    const int row0 = by * 128;
    const int col0 = bx * 128;

    const int sr  = wave * 32 + (lane >> 2);
    const int sco = (lane & 3) * 8;
    const ushort* gAh = Ah + (size_t)(row0 + sr) * K + sco;
    const ushort* gAl = ASPLIT ? (Al + (size_t)(row0 + sr) * K + sco) : nullptr;
    const ushort* gBh = Bh + (size_t)(col0 + sr) * K + sco;
    const ushort* gBl = Bl + (size_t)(col0 + sr) * K + sco;
    short* const ldst = lds_raw + wave * 1024;

    const int fr = lane & 15;
    const int fq = lane >> 4;
    const int ko = fq * 8;

    f32x4 acc[4][4] = {};

    for (int k0 = 0; k0 < K; k0 += 32) {
        const size_t K16 = (size_t)16 * K;
        gload16(gAh + k0,       ldst);
        gload16(gAh + k0 + K16, ldst + 512);
        if (ASPLIT) {
            gload16(gAl + k0,       ldst + 4096);
            gload16(gAl + k0 + K16, ldst + 4096 + 512);
        }
        gload16(gBh + k0,       ldst + 8192);
        gload16(gBh + k0 + K16, ldst + 8192 + 512);
        gload16(gBl + k0,       ldst + 12288);
        gload16(gBl + k0 + K16, ldst + 12288 + 512);
        __syncthreads();

        bf16x8 a_h[4], a_l[4], b_h[4], b_l[4];
        #pragma unroll
        for (int m = 0; m < 4; ++m) {
            const int r = wr * 64 + m * 16 + fr;
            a_h[m] = *(const bf16x8*)&lds_raw[r * 32 + ko];
            if (ASPLIT) a_l[m] = *(const bf16x8*)&lds_raw[4096 + r * 32 + ko];
        }
        #pragma unroll
        for (int n = 0; n < 4; ++n) {
            const int r = wc * 64 + n * 16 + fr;
            b_h[n] = *(const bf16x8*)&lds_raw[8192 + r * 32 + ko];
            b_l[n] = *(const bf16x8*)&lds_raw[12288 + r * 32 + ko];
        }

        #pragma unroll
        for (int m = 0; m < 4; ++m)
            #pragma unroll
            for (int n = 0; n < 4; ++n) {
                acc[m][n] = __builtin_amdgcn_mfma_f32_16x16x32_bf16(a_h[m], b_h[n], acc[m][n], 0, 0, 0);
                if (ASPLIT)
                    acc[m][n] = __builtin_amdgcn_mfma_f32_16x16x32_bf16(a_l[m], b_h[n], acc[m][n], 0, 0, 0);
                acc[m][n] = __builtin_amdgcn_mfma_f32_16x16x32_bf16(a_h[m], b_l[n], acc[m][n], 0, 0, 0);
            }
        __syncthreads();
    }

    float bv[4];
    #pragma unroll
    for (int n = 0; n < 4; ++n) {
        const int cc = col0 + wc * 64 + n * 16 + fr;
        bv[n] = bias[cc] * (cc < qcols ? QSCALE : 1.f);
    }

    if (OUTBF16) {
        short* wbuf = lds_raw + wave * 2048;
        #pragma unroll
        for (int t = 0; t < 2; ++t) {
            ushort* dst = (t == 0) ? Ch : Cl;
            #pragma unroll
            for (int half = 0; half < 2; ++half) {
                __syncthreads();
                #pragma unroll
                for (int m2 = 0; m2 < 2; ++m2) {
                    const int m = half * 2 + m2;
                    #pragma unroll
                    for (int j = 0; j < 4; ++j)
                        #pragma unroll
                        for (int n = 0; n < 4; ++n) {
                            const float o = acc[m][n][j] + bv[n];
                            const ushort hb = f2bf(o);
                            wbuf[(m2 * 16 + fq * 4 + j) * 64 + n * 16 + fr] =
                                (short)(t == 0 ? hb : f2bf(o - bf2f(hb)));
                        }
                }
                __syncthreads();
                #pragma unroll
                for (int i = 0; i < 4; ++i) {
                    const int r = i * 8 + (lane >> 3);
                    const bf16x8 v = *(const bf16x8*)&wbuf[r * 64 + (lane & 7) * 8];
                    *(bf16x8*)&dst[(size_t)(row0 + wr * 64 + half * 32 + r) * N
                                   + col0 + wc * 64 + (lane & 7) * 8] = v;
                }
            }
        }
    } else {
        float* fbuf = (float*)lds_raw + wave * 2048;
        #pragma unroll
        for (int half = 0; half < 2; ++half) {
            __syncthreads();
            #pragma unroll
            for (int m2 = 0; m2 < 2; ++m2) {
                const int m = half * 2 + m2;
                #pragma unroll
                for (int j = 0; j < 4; ++j)
                    #pragma unroll
                    for (int n = 0; n < 4; ++n)
                        fbuf[(m2 * 16 + fq * 4 + j) * 64 + n * 16 + fr] = acc[m][n][j] + bv[n];
            }
            __syncthreads();
            #pragma unroll
            for (int i = 0; i < 8; ++i) {
                const int r = i * 4 + (lane >> 4);
                const float4 v = *(const float4*)&fbuf[r * 64 + (lane & 15) * 4];
                *(float4*)&Cf[(size_t)(row0 + wr * 64 + half * 32 + r) * N
                              + col0 + wc * 64 + (lane & 15) * 4] = v;
            }
        }
    }
}

// ---------------------------------------------------------------------------
// MFMA flash attention (causal).  8 waves x 16 q-rows; KBLK 64.
// Round-8: log2-domain softmax (exp2, scale pre-folded into q), cvt_pk
// bf16 packing, raw-p l-sum, defer-max rescale (T13), XCD block swizzle.
// ---------------------------------------------------------------------------
__global__ __launch_bounds__(512, 4) void flash_attn_mfma(
    const ushort* __restrict__ qkvh, const ushort* __restrict__ qkvl,
    const ushort* __restrict__ vth, ushort* __restrict__ ath)
{
    __shared__ __align__(16) short Kh[64][64];
    __shared__ __align__(16) short Kl[64][64];
    __shared__ __align__(16) short Vs[64][64];
    __shared__ __align__(16) short Pw[8][2][16][72];

    // XCD swizzle: grid (16,16,4) -> nwg 1024, 128 per XCD
    const uint flat = blockIdx.x + (blockIdx.y << 4) + (blockIdx.z << 8);
    const uint swzb = (flat & 7) * 128 + (flat >> 3);
    const int q0 = (int)(swzb & 15) * 128;
    const int h  = (int)(swzb >> 4) & 15;
    const int b  = (int)(swzb >> 8);

    const int tid  = threadIdx.x;
    const int wave = tid >> 6;
    const int lane = tid & 63;
    const int fr = lane & 15;
    const int g  = lane >> 4;
    const int qw = q0 + wave * 16;
    const int qg = qw + fr;

    const size_t qrow = ((size_t)(b * TSEQ + qg)) * (3 * N_EMBD) + h * HD + 8 * g;
    const bf16x8 qh0 = *(const bf16x8*)&qkvh[qrow];
    const bf16x8 qh1 = *(const bf16x8*)&qkvh[qrow + 32];
    const bf16x8 ql0 = *(const bf16x8*)&qkvl[qrow];
    const bf16x8 ql1 = *(const bf16x8*)&qkvl[qrow + 32];

    f32x4 O[4] = {};
    float mrun = -1e30f, lrun = 0.f;

    const int sr  = tid >> 3;
    const int su  = tid & 7;
    const int spu = (su ^ (sr & 7)) * 8;
    const int sc  = su * 8;
    const ushort* kgh = qkvh + ((size_t)(b * TSEQ + sr)) * (3 * N_EMBD) + N_EMBD + h * HD + sc;
    const ushort* kgl = qkvl + ((size_t)(b * TSEQ + sr)) * (3 * N_EMBD) + N_EMBD + h * HD + sc;
    const ushort* vg  = vth + (((size_t)(b * N_HEAD + h)) * HD + sr) * TSEQ + sc;

    const int x7  = fr & 7;
    const int ru0 = (g ^ x7) * 8;
    const int ru1 = ((4 + g) ^ x7) * 8;

    const int nt = q0 / 64 + 2;

    float4 nkh = *(const float4*)(kgh);
    float4 nkl = *(const float4*)(kgl);
    float4 nv  = *(const float4*)(vg);

    for (int kt = 0; kt < nt; ++kt) {
        __syncthreads();
        *(float4*)&Kh[sr][spu] = nkh;
        *(float4*)&Kl[sr][spu] = nkl;
        *(float4*)&Vs[sr][spu] = nv;
        __syncthreads();

        if (kt + 1 < nt) {
            nkh = *(const float4*)(kgh + (size_t)(kt + 1) * 64 * 3 * N_EMBD);
            nkl = *(const float4*)(kgl + (size_t)(kt + 1) * 64 * 3 * N_EMBD);
            nv  = *(const float4*)(vg + (kt + 1) * 64);
        }

        if (kt * 64 > qw + 15) continue;

        // ---- QK^T (scores already in log2 domain via folded scale) ----
        f32x4 s[4] = {};
        __builtin_amdgcn_s_setprio(1);
        #pragma unroll
        for (int kf = 0; kf < 4; ++kf) {
            const int kr = kf * 16 + fr;
            const bf16x8 kh0 = *(const bf16x8*)&Kh[kr][ru0];
            const bf16x8 kl0 = *(const bf16x8*)&Kl[kr][ru0];
            const bf16x8 kh1 = *(const bf16x8*)&Kh[kr][ru1];
            const bf16x8 kl1 = *(const bf16x8*)&Kl[kr][ru1];
            s[kf] = __builtin_amdgcn_mfma_f32_16x16x32_bf16(kh0, qh0, s[kf], 0, 0, 0);
            s[kf] = __builtin_amdgcn_mfma_f32_16x16x32_bf16(kl0, qh0, s[kf], 0, 0, 0);
            s[kf] = __builtin_amdgcn_mfma_f32_16x16x32_bf16(kh0, ql0, s[kf], 0, 0, 0);
            s[kf] = __builtin_amdgcn_mfma_f32_16x16x32_bf16(kh1, qh1, s[kf], 0, 0, 0);
            s[kf] = __builtin_amdgcn_mfma_f32_16x16x32_bf16(kl1, qh1, s[kf], 0, 0, 0);
            s[kf] = __builtin_amdgcn_mfma_f32_16x16x32_bf16(kh1, ql1, s[kf], 0, 0, 0);
        }
        __builtin_amdgcn_s_setprio(0);

        // ---- causal mask + per-q max ----
        const bool dm = (kt * 64 + 63 > qw);
        float tmax = -1e30f;
        #pragma unroll
        for (int kf = 0; kf < 4; ++kf)
            #pragma unroll
            for (int j = 0; j < 4; ++j) {
                float v = s[kf][j];
                if (dm && (kt * 64 + kf * 16 + 4 * g + j > qg)) v = -1e30f;
                s[kf][j] = v;
                tmax = fmaxf(tmax, v);
            }
        tmax = fmaxf(tmax, __shfl_xor(tmax, 16));
        tmax = fmaxf(tmax, __shfl_xor(tmax, 32));

        // ---- defer-max (T13): rescale only when max grew past threshold ----
        float mn = mrun;
        if (!__all(tmax <= mrun + 8.f)) {
            mn = fmaxf(mrun, tmax);
            const float sf = fexp2(mrun - mn);
            mrun = mn;
            lrun *= sf;
            #pragma unroll
            for (int df = 0; df < 4; ++df)
                #pragma unroll
                for (int j = 0; j < 4; ++j) O[df][j] *= sf;
        }

        // ---- P = exp2(S-m): cvt_pk hi, residual lo; l from raw p ----
        #pragma unroll
        for (int kf = 0; kf < 4; ++kf) {
            const float p0 = fexp2(s[kf][0] - mn);
            const float p1 = fexp2(s[kf][1] - mn);
            const float p2 = fexp2(s[kf][2] - mn);
            const float p3 = fexp2(s[kf][3] - mn);
            lrun += (p0 + p1) + (p2 + p3);
            uint hw0, hw1, lw0, lw1;
            asm("v_cvt_pk_bf16_f32 %0, %1, %2" : "=v"(hw0) : "v"(p0), "v"(p1));
            asm("v_cvt_pk_bf16_f32 %0, %1, %2" : "=v"(hw1) : "v"(p2), "v"(p3));
            const float r0 = p0 - __uint_as_float(hw0 << 16);
            const float r1 = p1 - __uint_as_float(hw0 & 0xFFFF0000u);
            const float r2 = p2 - __uint_as_float(hw1 << 16);
            const float r3 = p3 - __uint_as_float(hw1 & 0xFFFF0000u);
            asm("v_cvt_pk_bf16_f32 %0, %1, %2" : "=v"(lw0) : "v"(r0), "v"(r1));
            asm("v_cvt_pk_bf16_f32 %0, %1, %2" : "=v"(lw1) : "v"(r2), "v"(r3));
            const int kb = kf * 16 + 4 * g;
            *(uint*)&Pw[wave][0][fr][kb]     = hw0;
            *(uint*)&Pw[wave][0][fr][kb + 2] = hw1;
            *(uint*)&Pw[wave][1][fr][kb]     = lw0;
            *(uint*)&Pw[wave][1][fr][kb + 2] = lw1;
        }

        // ---- PV: O^T[d][q] += V^T x P  (2-term) ----
        #pragma unroll
        for (int c = 0; c < 2; ++c) {
            const bf16x8 pbh = *(const bf16x8*)&Pw[wave][0][fr][c * 32 + 8 * g];
            const bf16x8 pbl = *(const bf16x8*)&Pw[wave][1][fr][c * 32 + 8 * g];
            const int rvc = ((4 * c + g) ^ x7) * 8;
            __builtin_amdgcn_s_setprio(1);
            #pragma unroll
            for (int df = 0; df < 4; ++df) {
                const bf16x8 va = *(const bf16x8*)&Vs[df * 16 + fr][rvc];
                O[df] = __builtin_amdgcn_mfma_f32_16x16x32_bf16(va, pbh, O[df], 0, 0, 0);
                O[df] = __builtin_amdgcn_mfma_f32_16x16x32_bf16(va, pbl, O[df], 0, 0, 0);
            }
            __builtin_amdgcn_s_setprio(0);
        }
    }

    // ---- finalize ----
    lrun += __shfl_xor(lrun, 16);
    lrun += __shfl_xor(lrun, 32);
    const float inv = 1.f / lrun;

    float* Ol = (float*)&Pw[wave][0][0][0];
    #pragma unroll
    for (int df = 0; df < 4; ++df)
        #pragma unroll
        for (int j = 0; j < 4; ++j)
            Ol[fr * 68 + df * 16 + 4 * g + j] = O[df][j] * inv;

    const int q2 = lane >> 2;
    const int dl = (lane & 3) * 4;
    const size_t orow = ((size_t)(b * TSEQ + q0 + wave * 16 + q2)) * N_EMBD + h * HD;
    #pragma unroll
    for (int i = 0; i < 4; ++i) {
        const float4 y = *(const float4*)&Ol[q2 * 68 + dl + 16 * i];
        ushort4 o4;
        o4.x = f2bf(y.x); o4.y = f2bf(y.y); o4.z = f2bf(y.z); o4.w = f2bf(y.w);
        *(ushort4*)&ath[orow + dl + 16 * i] = o4;
    }
}

// ---------------------------------------------------------------------------
// Orchestration.  Workspace (184,549,376 B, unchanged layout):
// ---------------------------------------------------------------------------
extern "C" void kernel_launch(void* const* d_in, const int* in_sizes, int n_in,
                              void* d_out, int out_size, void* d_ws, size_t ws_size,
                              hipStream_t stream) {
    const float* x      = (const float*)d_in[0];
    const float* W_attn = (const float*)d_in[1];
    const float* b_attn = (const float*)d_in[2];
    const float* W_proj = (const float*)d_in[3];
    const float* b_proj = (const float*)d_in[4];
    float* out = (float*)d_out;
    (void)in_sizes; (void)n_in; (void)out_size; (void)ws_size;

    char* ws = (char*)d_ws;
    ushort* qkvh = (ushort*)ws; ws += (size_t)MROWS * 3 * N_EMBD * 2;
    ushort* qkvl = (ushort*)ws; ws += (size_t)MROWS * 3 * N_EMBD * 2;
    ushort* xh   = (ushort*)ws; ws += (size_t)MROWS * N_EMBD * 2;
    ushort* xl   = (ushort*)ws; ws += (size_t)MROWS * N_EMBD * 2;
    ushort* wah  = (ushort*)ws; ws += (size_t)3 * N_EMBD * N_EMBD * 2;
    ushort* wal  = (ushort*)ws; ws += (size_t)3 * N_EMBD * N_EMBD * 2;
    ushort* wph  = (ushort*)ws; ws += (size_t)N_EMBD * N_EMBD * 2;
    ushort* wpl  = (ushort*)ws; ws += (size_t)N_EMBD * N_EMBD * 2;
    ushort* vth  = (ushort*)ws; ws += (size_t)MROWS * N_EMBD * 2;
    ushort* ath  = (ushort*)ws;

    dim3 blk(256);

    split_bf16<<<dim3(MROWS * N_EMBD / 1024), blk, 0, stream>>>(x, xh, xl);
    // W_attn^T: q-columns (rows n < 1024 of the transpose) pre-scaled
    transpose_split<<<dim3(3 * N_EMBD / 32, N_EMBD / 32), blk, 0, stream>>>(
        W_attn, wah, wal, N_EMBD, 3 * N_EMBD, N_EMBD, QSCALE);
    transpose_split<<<dim3(N_EMBD / 32, N_EMBD / 32), blk, 0, stream>>>(
        W_proj, wph, wpl, N_EMBD, N_EMBD, 0, 1.f);

    // qkv = x @ W_attn + b_attn  -> bf16 hi/lo (q part pre-scaled via W,b)
    gemm_mfma<true, true><<<dim3(3 * N_EMBD / 128, MROWS / 128), blk, 0, stream>>>(
        xh, xl, wah, wal, b_attn, nullptr, qkvh, qkvl, MROWS, 3 * N_EMBD, N_EMBD,
        N_EMBD);

    // V^T
    transpose_v<<<dim3(TSEQ / 64, N_HEAD, BSZ), blk, 0, stream>>>(qkvh, vth);

    // attention
    flash_attn_mfma<<<dim3(TSEQ / 128, N_HEAD, BSZ), dim3(512), 0, stream>>>(
        qkvh, qkvl, vth, ath);

    // out = attout @ W_proj + b_proj  (A hi-only, 2-term)
    gemm_mfma<false, false><<<dim3(N_EMBD / 128, MROWS / 128), blk, 0, stream>>>(
        ath, nullptr, wph, wpl, b_proj, out, nullptr, nullptr, MROWS, N_EMBD, N_EMBD,
        0);
}